// Round 5
// baseline (277.643 us; speedup 1.0000x reference)
//
#include <hip/hip_runtime.h>

typedef __attribute__((ext_vector_type(8))) short short8;
typedef __attribute__((ext_vector_type(4))) float f32x4;

#define XP_ELEMS (32u * 66u * 66u * 128u)  /* 17,842,176 bf16 elements */
#define WT_ELEMS (256u * 1152u)            /* 294,912 bf16 elements */
#define WS_NEED  ((size_t)(XP_ELEMS + WT_ELEMS) * 2u)

typedef const __attribute__((address_space(1))) void* gp1_t;
typedef __attribute__((address_space(3))) void* lp3_t;

__device__ __forceinline__ void gload16(const void* g, void* l) {
  __builtin_amdgcn_global_load_lds((gp1_t)g, (lp3_t)l, 16, 0, 0);
}

__device__ __forceinline__ short f2bf(float f) {
  unsigned u = __float_as_uint(f);
  u = (u + 0x7FFFu + ((u >> 16) & 1u)) >> 16;  // RNE truncate to bf16
  return (short)u;
}

// Transpose one (b, y) plane: x[b][cin][y][px] fp32 -> x_p[b][y+1][px+1][cin] bf16.
__global__ __launch_bounds__(256) void prepass_x(const float* __restrict__ x,
                                                 short* __restrict__ xp) {
  __shared__ short lds[64 * 128];  // [px][cin, granule-swizzled], 16 KB
  const int y = blockIdx.x;   // 0..63
  const int b = blockIdx.y;   // 0..31
  const int t = threadIdx.x;

  const float* src = x + (long)b * 128 * 4096 + y * 64;
#pragma unroll
  for (int i = 0; i < 8; ++i) {
    int f4 = t + i * 256;          // 0..2047
    int cin = f4 >> 4, px4 = f4 & 15;
    float4 v = *(const float4*)(src + (long)cin * 4096 + px4 * 4);
    float vv[4] = {v.x, v.y, v.z, v.w};
#pragma unroll
    for (int j = 0; j < 4; ++j) {
      int px = px4 * 4 + j;
      int g = (cin >> 3) ^ ((px ^ (px >> 2)) & 15);
      lds[px * 128 + (g << 3) + (cin & 7)] = f2bf(vv[j]);
    }
  }
  __syncthreads();
  short* dst = xp + ((long)(b * 66 + y + 1) * 66 + 1) * 128;
#pragma unroll
  for (int i = 0; i < 4; ++i) {
    int f8 = t + i * 256;          // 0..1023
    int px = f8 >> 4, c8 = f8 & 15;
    int g = c8 ^ ((px ^ (px >> 2)) & 15);
    short8 v = *(const short8*)&lds[px * 128 + (g << 3)];
    *(short8*)(dst + (long)px * 128 + c8 * 8) = v;
  }
  short8 z = (short8)0;
  short* rowbase = xp + (long)(b * 66 + y + 1) * 66 * 128;
  if (t < 32) {
    int px = (t < 16) ? 0 : 65;
    int c8 = t & 15;
    *(short8*)(rowbase + (long)px * 128 + c8 * 8) = z;
  }
  if (y == 0) {
    short* r0 = xp + (long)(b * 66) * 66 * 128;
    for (int idx = t; idx < 66 * 16; idx += 256) *(short8*)(r0 + idx * 8) = z;
  }
  if (y == 63) {
    short* r65 = xp + ((long)(b * 66) + 65) * 66 * 128;
    for (int idx = t; idx < 66 * 16; idx += 256) *(short8*)(r65 + idx * 8) = z;
  }
}

// weight[cout][cin][kh][kw] fp32 -> w_t[cout][kh][kw][cin] bf16
__global__ __launch_bounds__(256) void prepass_w(const float* __restrict__ w,
                                                 short* __restrict__ wt) {
  int o    = blockIdx.x * 256 + threadIdx.x;  // < 294912 exactly
  int cout = o / 1152;
  int r    = o % 1152;
  int kh   = r / 384;
  int kw   = (r / 128) % 3;
  int cin  = r & 127;
  wt[o] = f2bf(w[((cout * 128 + cin) * 3 + kh) * 3 + kw]);
}

// Implicit-GEMM conv, multi-CTA overlap design:
//   Tile 128x128, 4 waves (2x2, 64x64/wave, acc[4][4]), BK=32, ring-3 LDS
//   (48 KiB/CTA) -> 3 CTAs co-resident per CU (independent barrier clocks:
//   one CTA's LDS-read burst / epilogue overlaps another's MFMA burst --
//   this breaks the block-lockstep LDS<->MFMA serialization that pinned the
//   1-CTA/CU 256^2 variants at 33% MfmaUtil).
//   Counted-vmcnt ring (round-1 verified ledger): stage chunk c+2 at top of
//   compute(c); certify c+1 via vmcnt(4) + raw s_barrier; drain only at tail.
//   Addressing/swizzle/frag-reads/epilogue verbatim from the verified
//   round-0 128^2 kernel (k-granule XOR swizzle, conflict-free, lane-linear
//   gload_lds destinations).
__global__ __launch_bounds__(256, 3) void conv_gemm(const short* __restrict__ xp,
                                                    const short* __restrict__ wt,
                                                    float* __restrict__ out) {
  __shared__ alignas(16) short Alds[3 * 128 * 32];  // 24 KB
  __shared__ alignas(16) short Blds[3 * 128 * 32];  // 24 KB
  const int tid   = threadIdx.x;
  const int w     = tid >> 6;   // wave id 0..3
  const int l     = tid & 63;
  const int l15   = l & 15;
  const int q     = l >> 4;
  const int ntile = blockIdx.x;       // 0..1023 (n-tiles of 128; never spans images)
  const int m0    = blockIdx.y << 7;  // 0 or 128

  // ---- staging thread decomposition: thread -> (row r, granule p)
  const int r  = tid >> 2;            // 0..63
  const int p  = tid & 3;
  const int cs = p ^ ((r >> 1) & 3);  // source k-granule (swizzle, self-inverse)
  const long aoff0 = (long)(m0 + r) * 1152 + (cs << 3);
  const long aoff1 = aoff0 + (long)64 * 1152;
  long boff0, boff1;
  {
    int n0 = (ntile << 7) + r;
    int bb = n0 >> 12, yy = (n0 >> 6) & 63, xx = n0 & 63;
    boff0 = ((long)(bb * 66 + yy) * 66 + xx) * 128 + (cs << 3);
    int n1 = n0 + 64;
    bb = n1 >> 12; yy = (n1 >> 6) & 63; xx = n1 & 63;
    boff1 = ((long)(bb * 66 + yy) * 66 + xx) * 128 + (cs << 3);
  }
  const int ldst0 = r * 32 + p * 8;   // LDS short-offset, rows 0..63
  const int ldst1 = ldst0 + 2048;     // rows 64..127

  // ---- frag read offsets (chunk-invariant; conflict-free, verified r0-r4)
  const int wm = (w >> 1) << 6;  // wave's 64-row offset in tile (M)
  const int wn = (w & 1) << 6;   // wave's 64-col offset in tile (N)
  int aRd[4], bRd[4];
#pragma unroll
  for (int i = 0; i < 4; ++i) {
    int rA = wm + (i << 4) + l15;
    aRd[i] = rA * 32 + ((q ^ ((rA >> 1) & 3)) << 3);
    int rB = wn + (i << 4) + l15;
    bRd[i] = rB * 32 + ((q ^ ((rB >> 1) & 3)) << 3);
  }

  f32x4 acc[4][4];
#pragma unroll
  for (int i = 0; i < 4; ++i)
#pragma unroll
    for (int j = 0; j < 4; ++j) acc[i][j] = (f32x4)0.f;

  // stage one 32-k chunk (A: 128x32 of wt, B: 128x32 of shifted xp) -> 4 loads
  auto STAGE = [&](int slot, int ks) {
    const int kq  = ks >> 2;            // khkw 0..8
    const int kh  = kq / 3, kw2 = kq - kh * 3;
    const int sB  = (kh * 66 + kw2) * 128 + ((ks & 3) << 5);
    const int ka  = ks << 5;
    short* Ad = &Alds[slot * 4096];
    short* Bd = &Blds[slot * 4096];
    gload16(wt + aoff0 + ka, Ad + ldst0);
    gload16(wt + aoff1 + ka, Ad + ldst1);
    gload16(xp + boff0 + sB, Bd + ldst0);
    gload16(xp + boff1 + sB, Bd + ldst1);
  };

  auto COMPUTE = [&](int slot) {
    const short* Ab = &Alds[slot * 4096];
    const short* Bb = &Blds[slot * 4096];
    short8 af[4], bf[4];
#pragma unroll
    for (int i = 0; i < 4; ++i) af[i] = *(const short8*)&Ab[aRd[i]];
#pragma unroll
    for (int j = 0; j < 4; ++j) bf[j] = *(const short8*)&Bb[bRd[j]];
    __builtin_amdgcn_s_setprio(1);
#pragma unroll
    for (int i = 0; i < 4; ++i)
#pragma unroll
      for (int j = 0; j < 4; ++j)
        acc[i][j] = __builtin_amdgcn_mfma_f32_16x16x32_bf16(af[i], bf[j],
                                                            acc[i][j], 0, 0, 0);
    __builtin_amdgcn_s_setprio(0);
  };

#define BAR()   __builtin_amdgcn_s_barrier()
#define VMC(n)  asm volatile("s_waitcnt vmcnt(" #n ")" ::: "memory")

  // ---- prologue: fill 2 of 3 ring slots; certify chunk 0 (4 of 8 loads)
  STAGE(0, 0);
  STAGE(1, 1);
  VMC(4);
  BAR();

  // ---- main loop: 36 chunks of BK=32.  Stage c+2 into slot (c+2)%3, compute
  // slot c%3, certify c+1 with vmcnt(4) (c+2's 4 loads stay in flight).
  // WAR on slot (c+2)%3 (last read at chunk c-1) is safe: those ds_reads
  // completed before the previous fence's barrier.
  int s_cur = 0, s_nxt = 1, s_stg = 2;
#pragma unroll 1
  for (int ks = 0; ks < 34; ++ks) {
    STAGE(s_stg, ks + 2);
    COMPUTE(s_cur);
    VMC(4);   // certify chunk ks+1
    BAR();
    int t0 = s_cur; s_cur = s_nxt; s_nxt = s_stg; s_stg = t0;
  }
  // ks=34: no stage; certify chunk 35 (drain)
  COMPUTE(s_cur);
  VMC(0);
  BAR();
  // ks=35
  COMPUTE(s_nxt);

  // ---- epilogue: C/D layout col=lane&15, row=quad*4+reg (verified r0)
  const int ngb = (ntile << 7) + wn;
  const int b   = ngb >> 12;
  const int yxb = ngb & 4095;
  float* outb = out + (long)b * (256 * 4096) + yxb + l15;
#pragma unroll
  for (int i = 0; i < 4; ++i) {
#pragma unroll
    for (int rr = 0; rr < 4; ++rr) {
      const int cout = m0 + wm + (i << 4) + q * 4 + rr;
      float* orow = outb + (long)cout * 4096;
#pragma unroll
      for (int j = 0; j < 4; ++j) orow[j * 16] = acc[i][j][rr];
    }
  }
#undef BAR
#undef VMC
}

// Correctness fallback if workspace is too small (slow, fp32 direct conv).
__global__ __launch_bounds__(256) void naive_conv(const float* __restrict__ x,
                                                  const float* __restrict__ wgt,
                                                  float* __restrict__ out) {
  long o = (long)blockIdx.x * 256 + threadIdx.x;
  int xx = (int)(o & 63);
  int y  = (int)((o >> 6) & 63);
  int co = (int)((o >> 12) & 255);
  int b  = (int)(o >> 20);
  float s = 0.f;
  for (int ci = 0; ci < 128; ++ci) {
    for (int kh = 0; kh < 3; ++kh) {
      int iy = y + kh - 1;
      if (iy < 0 || iy > 63) continue;
      for (int kw = 0; kw < 3; ++kw) {
        int ix = xx + kw - 1;
        if (ix < 0 || ix > 63) continue;
        s += x[((long)(b * 128 + ci) * 64 + iy) * 64 + ix] *
             wgt[((co * 128 + ci) * 3 + kh) * 3 + kw];
      }
    }
  }
  out[o] = s;
}

extern "C" void kernel_launch(void* const* d_in, const int* in_sizes, int n_in,
                              void* d_out, int out_size, void* d_ws, size_t ws_size,
                              hipStream_t stream) {
  (void)in_sizes; (void)n_in;
  const float* x   = (const float*)d_in[0];
  const float* wgt = (const float*)d_in[1];
  float* out = (float*)d_out;
  if (ws_size >= WS_NEED) {
    short* xp = (short*)d_ws;
    short* wt = xp + XP_ELEMS;
    prepass_x<<<dim3(64, 32), dim3(256), 0, stream>>>(x, xp);
    prepass_w<<<dim3(WT_ELEMS / 256), dim3(256), 0, stream>>>(wgt, wt);
    conv_gemm<<<dim3(1024, 2), dim3(256), 0, stream>>>(xp, wt, out);
  } else {
    naive_conv<<<dim3(out_size / 256), dim3(256), 0, stream>>>(x, wgt, out);
  }
}